// Round 4
// baseline (518.216 us; speedup 1.0000x reference)
//
#include <hip/hip_runtime.h>
#include <cmath>

// ---------------------------------------------------------------------------
// SpatialLinearAttention — bf16 MFMA GEMMs + fused softmax/context chain.
//   x:(2,256,16,64,64) f32, w_qkv:(768,256) f32, w_out:(256,256) f32, b_out:(256,)
// Per chunk of CF frames (j = fl*4096 + n):
//   C0: xbf_t[j][c] = bf16(x^T)                      (k-contiguous)
//   C1: wq_bf = bf16(w_qkv)                          (once)
//   K1: qkv_t[j][o] = MFMA(wq[o][c], xbf[j][c]); q tiles (o<256) get the
//       d-softmax (*1/sqrt(32)) fused in the epilogue.  k,v stored raw bf16.
//   S1: k_kstat1: per (fl, j-split): online (m,s) partials per k-col (256)
//   S2: k_kstat2: combine 16 partials -> (M, 1/S) per (fl, k-col)
//   CX: k_ctx: per (fl, j-split): P[h][d][e] += exp(k[d,j]-M_d) * v[e,j]
//   W2: k_w2fold: C = invS_d * sum_js P; W2[o][h*32+d] = sum_e w_out[o][..e]*C[d][e]
//   K5: out = MFMA(q[j][c2], W2[o][c2]) + b_out, fp32 direct store
//
// R1: LDS XOR swizzle on MFMA staging tiles (bank conflicts 8.4M -> 2.1M).
// R2: XCD-chunked bijective block swizzle (FETCH 199MB -> 35MB).
// R3: 1-deep dbuf + vmcnt(0): NEUTRAL — window (~250cyc) < L3/HBM latency.
// R4: (a) small L2-hot operand (wq / w2) now direct global->register with
//     1-step register prefetch — LDS reads and async16s per step halved
//     (LDS pipe was the MfmaUtil~20% ceiling: 96cyc LDS vs 78cyc MFMA/step).
//     (b) streamed operand staged 3-deep (mod-3 rotation) with COUNTED
//     vmcnt(6)/vmcnt(4) waits — loads stay in flight across barriers,
//     ~2.5 K-steps (~700cyc) of latency cover. Never vmcnt(0) in-loop.
// ---------------------------------------------------------------------------

typedef unsigned short u16;
typedef __attribute__((ext_vector_type(4))) unsigned short u16x4;
typedef __attribute__((ext_vector_type(8))) unsigned short u16x8;
typedef __attribute__((ext_vector_type(4))) unsigned int   u32x4;
typedef __attribute__((ext_vector_type(8))) short bf16x8;
typedef __attribute__((ext_vector_type(4))) float f32x4;

#define XCH_STRIDE 65536    // x stride over c: 16*4096
#define XB_STRIDE  16777216 // x stride over b: 256*16*4096

__device__ __forceinline__ float bf2f(u16 u) {
    union { unsigned int i; float f; } w; w.i = ((unsigned int)u) << 16; return w.f;
}
__device__ __forceinline__ u16 f2bf(float f) {
    union { float f; unsigned int i; } w; w.f = f;
    return (u16)((w.i + 0x7FFFu + ((w.i >> 16) & 1u)) >> 16);
}
__device__ __forceinline__ void async16(const void* g, void* l) {
    __builtin_amdgcn_global_load_lds(
        (const __attribute__((address_space(1))) unsigned int*)g,
        (__attribute__((address_space(3))) unsigned int*)l, 16, 0, 0);
}

// ---------------- C0: x (b,c,f,n) f32 -> xbf_t[(fl,n)][c] bf16 --------------
__global__ __launch_bounds__(256) void k_cvt_x(const float* __restrict__ x,
                                               u16* __restrict__ xbf, int fr0)
{
    const int tid = threadIdx.x;
    const int n0 = blockIdx.x * 64;
    const int c0 = blockIdx.y * 64;
    const int fl = blockIdx.z;
    const int frame = fr0 + fl, b = frame >> 4, f = frame & 15;
    const float* xb = x + (size_t)b * XB_STRIDE + (size_t)f * 4096;
    __shared__ float T[64][65];
    const int nn = tid & 63, cq = tid >> 6;
    #pragma unroll
    for (int r = 0; r < 16; ++r) {
        const int cl = r * 4 + cq;
        T[cl][nn] = xb[(size_t)(c0 + cl) * XCH_STRIDE + n0 + nn];
    }
    __syncthreads();
    const int jl = tid >> 2, c16 = (tid & 3) * 16;
    u16* dst = xbf + ((size_t)fl * 4096 + n0 + jl) * 256 + c0 + c16;
    u16x8 a, bv;
    #pragma unroll
    for (int i = 0; i < 8; ++i) a[i] = f2bf(T[c16 + i][jl]);
    #pragma unroll
    for (int i = 0; i < 8; ++i) bv[i] = f2bf(T[c16 + 8 + i][jl]);
    *(u16x8*)dst = a;
    *(u16x8*)(dst + 8) = bv;
}

// ---------------- C1: w_qkv f32 -> bf16 -------------------------------------
__global__ __launch_bounds__(256) void k_cvt_w(const float* __restrict__ w,
                                               u16* __restrict__ wbf)
{
    const int i = (blockIdx.x * 256 + threadIdx.x) * 8;
    u16x8 o;
    #pragma unroll
    for (int j = 0; j < 8; ++j) o[j] = f2bf(w[i + j]);
    *(u16x8*)(wbf + i) = o;
}

// ---------------- K1: qkv_t[j][o] MFMA, q-softmax fused in epilogue ---------
// grid: 1-D, CF*32*6 blocks; XCD-chunked swizzle, o fastest within XCD.
// A (wq) direct global->reg (L2-hot); B (xbf) staged 3-deep with counted vmcnt.
__global__ __launch_bounds__(256) void k_qkv_mfma(const u16* __restrict__ xbf,
                                                  const u16* __restrict__ wq,
                                                  u16* __restrict__ qkv)
{
    const int tid = threadIdx.x;
    const int lane = tid & 63, wave = tid >> 6;
    const int ln = lane & 15, quad = lane >> 4;
    const int wm = wave & 1, wn = wave >> 1;

    const int chunk = gridDim.x >> 3;
    const int newid = (blockIdx.x & 7) * chunk + (blockIdx.x >> 3);
    const int o0 = (newid % 6) * 128;   // M tile (wq rows) — fastest
    const int j0 = (newid / 6) * 128;   // N tile (x rows)

    // LDS: 3 x 8KB B-staging buffers (mod-3), overlaid with 34.8KB out-tile
    __shared__ __align__(16) u16 sm[128 * 136];

    f32x4 acc[4][4] = {};
    const int lrow = lane >> 2;
    // pre-swizzled global source: LDS slot (r, c) holds chunk c^((r>>1)&3)
    const int lk8 = ((lane & 3) ^ ((lrow >> 1) & 3)) * 8;
    // fragment-read swizzle: same XOR ((row>>1)&3 == (ln>>1)&3)
    const int sw8 = (quad ^ ((ln >> 1) & 3)) * 8;

    const u16* gB = xbf + (size_t)j0 * 256;
    const int r0 = wave * 32 + lrow;
    // A fragment base: direct global (no swizzle needed)
    const u16* gA0 = wq + (size_t)(o0 + wm * 64 + ln) * 256 + quad * 8;

    bf16x8 afr[2][4];

    // prologue: B(0)->buf0, A(0)->afr[0], B(1)->buf1; wait B(0), keep B(1) flying
    async16(gB + (size_t)r0 * 256 + lk8,        sm + (wave*2) * 512);
    async16(gB + (size_t)(r0+16) * 256 + lk8,   sm + (wave*2+1) * 512);
    #pragma unroll
    for (int mi = 0; mi < 4; ++mi)
        afr[0][mi] = *(const bf16x8*)(gA0 + mi * 16 * 256);
    async16(gB + (size_t)r0 * 256 + 32 + lk8,      sm + 4096 + (wave*2) * 512);
    async16(gB + (size_t)(r0+16) * 256 + 32 + lk8, sm + 4096 + (wave*2+1) * 512);
    asm volatile("s_waitcnt vmcnt(2)\n\ts_barrier" ::: "memory");

    #pragma unroll
    for (int t = 0; t < 8; ++t) {
        const u16* Bs = sm + (t % 3) * 4096;
        if (t < 6) {  // stage B(t+2) — lands 2 barriers from now
            u16* Bn = sm + ((t + 2) % 3) * 4096;
            const int kk2 = (t + 2) * 32;
            async16(gB + (size_t)r0 * 256 + kk2 + lk8,      Bn + (wave*2) * 512);
            async16(gB + (size_t)(r0+16) * 256 + kk2 + lk8, Bn + (wave*2+1) * 512);
        }
        if (t < 7) {  // prefetch A(t+1) into regs — survives the barrier
            const int kk1 = (t + 1) * 32;
            #pragma unroll
            for (int mi = 0; mi < 4; ++mi)
                afr[(t + 1) & 1][mi] = *(const bf16x8*)(gA0 + mi * 16 * 256 + kk1);
        }
        bf16x8 bfv[4];
        #pragma unroll
        for (int ni = 0; ni < 4; ++ni)
            bfv[ni] = *(const bf16x8*)&Bs[(wn * 64 + ni * 16 + ln) * 32 + sw8];
        #pragma unroll
        for (int mi = 0; mi < 4; ++mi)
            #pragma unroll
            for (int ni = 0; ni < 4; ++ni)
                acc[mi][ni] = __builtin_amdgcn_mfma_f32_16x16x32_bf16(
                    afr[t & 1][mi], bfv[ni], acc[mi][ni], 0, 0, 0);
        // counted waits: oldest 2 outstanding (= B(t+1) stage) must land;
        // B(t+2) + A(t+1) stay in flight across the barrier.
        if (t < 6)       asm volatile("s_waitcnt vmcnt(6)\n\ts_barrier" ::: "memory");
        else if (t == 6) asm volatile("s_waitcnt vmcnt(4)\n\ts_barrier" ::: "memory");
    }

    // Assemble [j][o] bf16 tile in LDS (stride 136)
    __syncthreads();
    u16* outl = sm;
    #pragma unroll
    for (int mi = 0; mi < 4; ++mi)
        #pragma unroll
        for (int ni = 0; ni < 4; ++ni) {
            const int jl = wn * 64 + ni * 16 + ln;
            const int ob = wm * 64 + mi * 16 + quad * 4;
            u16x4 u;
            u[0] = f2bf(acc[mi][ni][0]); u[1] = f2bf(acc[mi][ni][1]);
            u[2] = f2bf(acc[mi][ni][2]); u[3] = f2bf(acc[mi][ni][3]);
            *(u16x4*)&outl[jl * 136 + ob] = u;
        }
    __syncthreads();

    if (o0 < 256) {
        // q tiles: softmax over each 32-col head group, * 1/sqrt(32)
        #pragma unroll
        for (int t = 0; t < 2; ++t) {
            const int idx = t * 256 + tid;
            const int r = idx >> 2, hh = idx & 3;
            const u16* p = &outl[r * 136 + hh * 32];
            float v[32];
            float m = -1e30f;
            #pragma unroll
            for (int g = 0; g < 4; ++g) {
                u16x8 u = *(const u16x8*)(p + g * 8);
                #pragma unroll
                for (int i = 0; i < 8; ++i) {
                    v[g * 8 + i] = bf2f(u[i]);
                    m = fmaxf(m, v[g * 8 + i]);
                }
            }
            float s = 0.f;
            #pragma unroll
            for (int i = 0; i < 32; ++i) { v[i] = __expf(v[i] - m); s += v[i]; }
            const float inv = 0.17677669529663687f / s;
            u16* q = qkv + (size_t)(j0 + r) * 768 + o0 + hh * 32;
            #pragma unroll
            for (int g = 0; g < 4; ++g) {
                u16x8 ov;
                #pragma unroll
                for (int i = 0; i < 8; ++i) ov[i] = f2bf(v[g * 8 + i] * inv);
                *(u16x8*)(q + g * 8) = ov;
            }
        }
    } else {
        #pragma unroll
        for (int r = 0; r < 8; ++r) {
            const int row = r * 16 + (tid >> 4);
            const int cb = (tid & 15) * 8;
            u32x4 v = *(const u32x4*)&outl[row * 136 + cb];
            *(u32x4*)(qkv + (size_t)(j0 + row) * 768 + o0 + cb) = v;
        }
    }
}

// ---------------- S1: online (m,s) partials per k-col, per (fl, j-split) ----
__global__ __launch_bounds__(256) void k_kstat1(const u16* __restrict__ qkv,
                                                float* __restrict__ sp)
{
    const int js = blockIdx.x, fl = blockIdx.y;
    const int tid = threadIdx.x;
    const int s = tid >> 5, g = tid & 31;
    const u16* base = qkv + ((size_t)fl * 4096 + js * 256 + s) * 768 + 256 + g * 8;
    float m[8], sm[8];
    #pragma unroll
    for (int i = 0; i < 8; ++i) { m[i] = -1e30f; sm[i] = 0.f; }
    for (int it = 0; it < 32; ++it) {
        u16x8 u = *(const u16x8*)(base + (size_t)it * 8 * 768);
        #pragma unroll
        for (int i = 0; i < 8; ++i) {
            float v = bf2f(u[i]);
            float nm = fmaxf(m[i], v);
            sm[i] = sm[i] * __expf(m[i] - nm) + __expf(v - nm);
            m[i] = nm;
        }
    }
    __shared__ float Lm[8][256], Ls[8][256];
    #pragma unroll
    for (int i = 0; i < 8; ++i) { Lm[s][g * 8 + i] = m[i]; Ls[s][g * 8 + i] = sm[i]; }
    __syncthreads();
    const int col = tid;
    float M = -1e30f;
    #pragma unroll
    for (int k = 0; k < 8; ++k) M = fmaxf(M, Lm[k][col]);
    float S = 0.f;
    #pragma unroll
    for (int k = 0; k < 8; ++k) S += Ls[k][col] * __expf(Lm[k][col] - M);
    float* o = sp + (((size_t)fl * 16 + js) * 256 + col) * 2;
    o[0] = M; o[1] = S;
}

// ---------------- S2: combine 16 partials -> (M, 1/S) -----------------------
__global__ __launch_bounds__(256) void k_kstat2(const float* __restrict__ sp,
                                                float* __restrict__ stat)
{
    const int fl = blockIdx.x, col = threadIdx.x;
    float mv[16], sv[16];
    float M = -1e30f;
    #pragma unroll
    for (int js = 0; js < 16; ++js) {
        const float* p = sp + (((size_t)fl * 16 + js) * 256 + col) * 2;
        mv[js] = p[0]; sv[js] = p[1];
        M = fmaxf(M, mv[js]);
    }
    float S = 0.f;
    #pragma unroll
    for (int js = 0; js < 16; ++js) S += sv[js] * __expf(mv[js] - M);
    float* o = stat + ((size_t)fl * 256 + col) * 2;
    o[0] = M; o[1] = 1.0f / S;
}

// ---------------- CX: P[h][d][e] += exp(k-M)*v, per (fl, j-split) -----------
__global__ __launch_bounds__(256) void k_ctx(const u16* __restrict__ qkv,
                                             const float* __restrict__ stat,
                                             float* __restrict__ P)
{
    const int js = blockIdx.x, fl = blockIdx.y;
    const int tid = threadIdx.x;
    const int ls = tid >> 5, lg = tid & 31;                  // staging role
    const int h = tid >> 5, dg = (tid >> 3) & 3, eg = tid & 7;  // acc role
    const int d0 = dg * 8, e0 = eg * 4;

    float Mg[8];
    #pragma unroll
    for (int i = 0; i < 8; ++i) Mg[i] = stat[((size_t)fl * 256 + lg * 8 + i) * 2];

    __shared__ float expk[8][264], vbuf[8][264];
    f32x4 acc[8] = {};
    const u16* kbase = qkv + ((size_t)fl * 4096 + js * 256 + ls) * 768 + 256 + lg * 8;

    for (int ch = 0; ch < 32; ++ch) {
        const u16* kp = kbase + (size_t)ch * 8 * 768;
        u16x8 ku = *(const u16x8*)kp;
        u16x8 vu = *(const u16x8*)(kp + 256);
        __syncthreads();
        #pragma unroll
        for (int i = 0; i < 8; ++i) {
            expk[ls][lg * 8 + i] = __expf(bf2f(ku[i]) - Mg[i]);
            vbuf[ls][lg * 8 + i] = bf2f(vu[i]);
        }
        __syncthreads();
        #pragma unroll
        for (int rr = 0; rr < 8; ++rr) {
            f32x4 w0 = *(const f32x4*)&expk[rr][h * 32 + d0];
            f32x4 w1 = *(const f32x4*)&expk[rr][h * 32 + d0 + 4];
            f32x4 vv = *(const f32x4*)&vbuf[rr][h * 32 + e0];
            #pragma unroll
            for (int ei = 0; ei < 4; ++ei) {
                acc[0][ei] = fmaf(w0[0], vv[ei], acc[0][ei]);
                acc[1][ei] = fmaf(w0[1], vv[ei], acc[1][ei]);
                acc[2][ei] = fmaf(w0[2], vv[ei], acc[2][ei]);
                acc[3][ei] = fmaf(w0[3], vv[ei], acc[3][ei]);
                acc[4][ei] = fmaf(w1[0], vv[ei], acc[4][ei]);
                acc[5][ei] = fmaf(w1[1], vv[ei], acc[5][ei]);
                acc[6][ei] = fmaf(w1[2], vv[ei], acc[6][ei]);
                acc[7][ei] = fmaf(w1[3], vv[ei], acc[7][ei]);
            }
        }
    }
    float* o = P + ((size_t)fl * 16 + js) * 8192 + (h * 32 + d0) * 32 + e0;
    #pragma unroll
    for (int di = 0; di < 8; ++di) *(f32x4*)(o + di * 32) = acc[di];
}

// ---------------- W2: sum partials, *invS, fold w_out -> W2 bf16 ------------
__global__ __launch_bounds__(256) void k_w2fold(const float* __restrict__ P,
                                                const float* __restrict__ stat,
                                                const float* __restrict__ w_out,
                                                u16* __restrict__ w2)
{
    const int h = blockIdx.x, fl = blockIdx.y;
    const int tid = threadIdx.x;
    __shared__ float Cs[32 * 33];

    const float* p0 = P + (size_t)fl * 16 * 8192 + h * 1024 + tid * 4;
    f32x4 sum = {0.f, 0.f, 0.f, 0.f};
    #pragma unroll
    for (int js = 0; js < 16; ++js) {
        f32x4 v = *(const f32x4*)(p0 + (size_t)js * 8192);
        sum[0] += v[0]; sum[1] += v[1]; sum[2] += v[2]; sum[3] += v[3];
    }
    const int d = tid >> 3, e4 = (tid & 7) * 4;
    const float inv = stat[((size_t)fl * 256 + h * 32 + d) * 2 + 1];
    Cs[d * 33 + e4 + 0] = sum[0] * inv;
    Cs[d * 33 + e4 + 1] = sum[1] * inv;
    Cs[d * 33 + e4 + 2] = sum[2] * inv;
    Cs[d * 33 + e4 + 3] = sum[3] * inv;
    __syncthreads();

    const int o = tid;
    float a2[32];
    #pragma unroll
    for (int dd = 0; dd < 32; ++dd) a2[dd] = 0.f;
    for (int e = 0; e < 32; ++e) {
        const float wv = w_out[(size_t)o * 256 + h * 32 + e];
        #pragma unroll
        for (int dd = 0; dd < 32; ++dd) a2[dd] = fmaf(wv, Cs[dd * 33 + e], a2[dd]);
    }
    u16* wp = w2 + (size_t)fl * 65536 + (size_t)o * 256 + h * 32;
    #pragma unroll
    for (int g = 0; g < 4; ++g) {
        u16x8 ov;
        #pragma unroll
        for (int i = 0; i < 8; ++i) ov[i] = f2bf(a2[g * 8 + i]);
        *(u16x8*)(wp + g * 8) = ov;
    }
}

// ---------------- K5: out = MFMA(q, W2) + b_out, fp32 direct store ----------
// grid: 1-D, CF*32*2 blocks; XCD-chunked swizzle, o fastest within XCD.
// A (q) staged 3-deep; B (w2, L2-hot) direct global->reg with prefetch.
__global__ __launch_bounds__(256) void k_out_mfma(const u16* __restrict__ qkv,
                                                  const u16* __restrict__ w2,
                                                  const float* __restrict__ b_out,
                                                  float* __restrict__ out, int fr0)
{
    const int tid = threadIdx.x;
    const int lane = tid & 63, wave = tid >> 6;
    const int ln = lane & 15, quad = lane >> 4;
    const int wm = wave & 1, wn = wave >> 1;

    const int chunk = gridDim.x >> 3;
    const int newid = (blockIdx.x & 7) * chunk + (blockIdx.x >> 3);
    const int o0 = (newid & 1) * 128;   // N tile (W2 rows) — fastest
    const int j0 = (newid >> 1) * 128;  // M tile (q rows, local j)

    const int fl = j0 >> 12;
    const int frame = fr0 + fl, b = frame >> 4, f = frame & 15;
    const int nb = j0 & 4095;
    const u16* w2f = w2 + (size_t)fl * 65536;

    __shared__ __align__(16) u16 sm[12288];   // 3 x 8KB A-staging

    f32x4 acc[4][4] = {};
    const int lrow = lane >> 2;
    const int lk8 = ((lane & 3) ^ ((lrow >> 1) & 3)) * 8;   // pre-swizzled src
    const int sw8 = (quad ^ ((ln >> 1) & 3)) * 8;           // swizzled ds_read

    const u16* gA = qkv + (size_t)j0 * 768;
    const int r0 = wave * 32 + lrow;
    const u16* gB0 = w2f + (size_t)(o0 + wn * 64 + ln) * 256 + quad * 8;

    bf16x8 bfr[2][4];

    // prologue: A(0)->buf0, B(0)->bfr[0], A(1)->buf1
    async16(gA + (size_t)r0 * 768 + lk8,        sm + (wave*2) * 512);
    async16(gA + (size_t)(r0+16) * 768 + lk8,   sm + (wave*2+1) * 512);
    #pragma unroll
    for (int ni = 0; ni < 4; ++ni)
        bfr[0][ni] = *(const bf16x8*)(gB0 + ni * 16 * 256);
    async16(gA + (size_t)r0 * 768 + 32 + lk8,      sm + 4096 + (wave*2) * 512);
    async16(gA + (size_t)(r0+16) * 768 + 32 + lk8, sm + 4096 + (wave*2+1) * 512);
    asm volatile("s_waitcnt vmcnt(2)\n\ts_barrier" ::: "memory");

    #pragma unroll
    for (int t = 0; t < 8; ++t) {
        const u16* As = sm + (t % 3) * 4096;
        if (t < 6) {
            u16* An = sm + ((t + 2) % 3) * 4096;
            const int kk2 = (t + 2) * 32;
            async16(gA + (size_t)r0 * 768 + kk2 + lk8,      An + (wave*2) * 512);
            async16(gA + (size_t)(r0+16) * 768 + kk2 + lk8, An + (wave*2+1) * 512);
        }
        if (t < 7) {
            const int kk1 = (t + 1) * 32;
            #pragma unroll
            for (int ni = 0; ni < 4; ++ni)
                bfr[(t + 1) & 1][ni] = *(const bf16x8*)(gB0 + ni * 16 * 256 + kk1);
        }
        bf16x8 af[4];
        #pragma unroll
        for (int mi = 0; mi < 4; ++mi)
            af[mi] = *(const bf16x8*)&As[(wm * 64 + mi * 16 + ln) * 32 + sw8];
        #pragma unroll
        for (int mi = 0; mi < 4; ++mi)
            #pragma unroll
            for (int ni = 0; ni < 4; ++ni)
                acc[mi][ni] = __builtin_amdgcn_mfma_f32_16x16x32_bf16(
                    af[mi], bfr[t & 1][ni], acc[mi][ni], 0, 0, 0);
        if (t < 6)       asm volatile("s_waitcnt vmcnt(6)\n\ts_barrier" ::: "memory");
        else if (t == 6) asm volatile("s_waitcnt vmcnt(4)\n\ts_barrier" ::: "memory");
    }

    float* obase = out + (size_t)b * XB_STRIDE + (size_t)f * 4096;
    #pragma unroll
    for (int ni = 0; ni < 4; ++ni) {
        const int o = o0 + wn * 64 + ni * 16 + ln;
        const float bias = b_out[o];
        #pragma unroll
        for (int mi = 0; mi < 4; ++mi) {
            const int jn = nb + wm * 64 + mi * 16 + quad * 4;
            f32x4 v = acc[mi][ni];
            v[0] += bias; v[1] += bias; v[2] += bias; v[3] += bias;
            *(f32x4*)(obase + (size_t)o * XCH_STRIDE + jn) = v;
        }
    }
}

// ---------------------------------------------------------------------------
extern "C" void kernel_launch(void* const* d_in, const int* in_sizes, int n_in,
                              void* d_out, int out_size, void* d_ws, size_t ws_size,
                              hipStream_t stream)
{
    const float* x     = (const float*)d_in[0];
    const float* w_qkv = (const float*)d_in[1];
    const float* w_out = (const float*)d_in[2];
    const float* b_out = (const float*)d_in[3];
    float* out = (float*)d_out;

    // ws per frame: xbf 2MB + qkv 6MB + w2 128KB + sp 32KB + stat 2KB + P 512KB
    const size_t per_frame = (size_t)4096 * 256 * 2 + (size_t)4096 * 768 * 2
                           + 65536 * 2 + 16 * 512 * 4 + 512 * 4 + 16 * 8192 * 4;
    const size_t wq_bytes = 768 * 256 * 2;
    int CF = 32;
    while (CF > 1 && (size_t)CF * per_frame + wq_bytes > ws_size) CF >>= 1;

    u16* wq_bf  = (u16*)d_ws;
    u16* xbf    = wq_bf + 768 * 256;
    u16* qkv    = xbf + (size_t)CF * 4096 * 256;
    u16* w2     = qkv + (size_t)CF * 4096 * 768;
    float* sp   = (float*)(w2 + (size_t)CF * 65536);
    float* stat = sp + (size_t)CF * 16 * 256 * 2;
    float* P    = stat + (size_t)CF * 256 * 2;

    k_cvt_w<<<96, 256, 0, stream>>>(w_qkv, wq_bf);
    for (int fr0 = 0; fr0 < 32; fr0 += CF) {
        k_cvt_x   <<<dim3(64, 4, CF), 256, 0, stream>>>(x, xbf, fr0);
        k_qkv_mfma<<<CF * 32 * 6, 256, 0, stream>>>(xbf, wq_bf, qkv);
        k_kstat1  <<<dim3(16, CF), 256, 0, stream>>>(qkv, sp);
        k_kstat2  <<<CF, 256, 0, stream>>>(sp, stat);
        k_ctx     <<<dim3(16, CF), 256, 0, stream>>>(qkv, stat, P);
        k_w2fold  <<<dim3(8, CF), 256, 0, stream>>>(P, stat, w_out, w2);
        k_out_mfma<<<CF * 32 * 2, 256, 0, stream>>>(qkv, w2, b_out, out, fr0);
    }
}

// Round 5
// 470.388 us; speedup vs baseline: 1.1017x; 1.1017x over previous
//
#include <hip/hip_runtime.h>
#include <cmath>

// ---------------------------------------------------------------------------
// SpatialLinearAttention — bf16 MFMA GEMMs + fused softmax/context chain.
//   x:(2,256,16,64,64) f32, w_qkv:(768,256) f32, w_out:(256,256) f32, b_out:(256,)
// Per chunk of CF frames (j = fl*4096 + n):
//   C0: xbf_t[j][c] = bf16(x^T)                      (k-contiguous)
//   C1: wq_f = bf16(w_qkv) in MFMA-FRAGMENT ORDER    (once)
//   K1: qkv_t[j][o] = MFMA(wq[o][c], xbf[j][c]); q tiles (o<256) get the
//       d-softmax (*1/sqrt(32)) fused in the epilogue.  k,v stored raw bf16.
//   S1/S2: k-softmax stats (M, 1/S) per (fl, k-col)
//   CX: k_ctx: P[h][d][e] += exp(k[d,j]-M_d) * v[e,j]
//   W2: k_w2fold: fold w_out with context -> w2_f bf16 (FRAGMENT ORDER)
//   K5: out = MFMA(q[j][c2], W2[o][c2]) + b_out, fp32 direct store
//
// R1: LDS XOR swizzle on staging tiles (bank conflicts 8.4M -> 2.1M).
// R2: XCD-chunked bijective block swizzle (FETCH 199MB -> 35MB).
// R3: 1-deep dbuf + vmcnt(0): NEUTRAL (window < latency; vmcnt(0) drains).
// R4: A-direct-from-global FAILED (139us): B-stage issued before A-reg loads
//     -> compiler's A-wait drained the B prefetch; A frags scattered 16 lines.
// R5: fix both: weights stored in FRAGMENT ORDER (lane l's 16B at base+l*16,
//     perfectly coalesced reg loads, no LDS transit for the small operand);
//     issue order A-regs FIRST then B-stage; counted vmcnt(6)/(4) proven to
//     drain B(t+1) under any intra-region compiler interleave. LDS traffic
//     per block-step 48KB -> 24KB (was the 4:1 LDS:MFMA ceiling).
// ---------------------------------------------------------------------------

typedef unsigned short u16;
typedef __attribute__((ext_vector_type(4))) unsigned short u16x4;
typedef __attribute__((ext_vector_type(8))) unsigned short u16x8;
typedef __attribute__((ext_vector_type(4))) unsigned int   u32x4;
typedef __attribute__((ext_vector_type(8))) short bf16x8;
typedef __attribute__((ext_vector_type(4))) float f32x4;

#define XCH_STRIDE 65536    // x stride over c: 16*4096
#define XB_STRIDE  16777216 // x stride over b: 256*16*4096

__device__ __forceinline__ float bf2f(u16 u) {
    union { unsigned int i; float f; } w; w.i = ((unsigned int)u) << 16; return w.f;
}
__device__ __forceinline__ u16 f2bf(float f) {
    union { float f; unsigned int i; } w; w.f = f;
    return (u16)((w.i + 0x7FFFu + ((w.i >> 16) & 1u)) >> 16);
}
__device__ __forceinline__ void async16(const void* g, void* l) {
    __builtin_amdgcn_global_load_lds(
        (const __attribute__((address_space(1))) unsigned int*)g,
        (__attribute__((address_space(3))) unsigned int*)l, 16, 0, 0);
}

// ---------------- C0: x (b,c,f,n) f32 -> xbf_t[(fl,n)][c] bf16 --------------
__global__ __launch_bounds__(256) void k_cvt_x(const float* __restrict__ x,
                                               u16* __restrict__ xbf, int fr0)
{
    const int tid = threadIdx.x;
    const int n0 = blockIdx.x * 64;
    const int c0 = blockIdx.y * 64;
    const int fl = blockIdx.z;
    const int frame = fr0 + fl, b = frame >> 4, f = frame & 15;
    const float* xb = x + (size_t)b * XB_STRIDE + (size_t)f * 4096;
    __shared__ float T[64][65];
    const int nn = tid & 63, cq = tid >> 6;
    #pragma unroll
    for (int r = 0; r < 16; ++r) {
        const int cl = r * 4 + cq;
        T[cl][nn] = xb[(size_t)(c0 + cl) * XCH_STRIDE + n0 + nn];
    }
    __syncthreads();
    const int jl = tid >> 2, c16 = (tid & 3) * 16;
    u16* dst = xbf + ((size_t)fl * 4096 + n0 + jl) * 256 + c0 + c16;
    u16x8 a, bv;
    #pragma unroll
    for (int i = 0; i < 8; ++i) a[i] = f2bf(T[c16 + i][jl]);
    #pragma unroll
    for (int i = 0; i < 8; ++i) bv[i] = f2bf(T[c16 + 8 + i][jl]);
    *(u16x8*)dst = a;
    *(u16x8*)(dst + 8) = bv;
}

// ---------------- C1: w_qkv f32 -> wq_f bf16 in MFMA-fragment order ---------
// chunk idx = (((ob*8 + kk)*2 + wm)*4 + mi)*64 + lane; content e=0..7:
//   w_qkv[(ob*128 + wm*64 + mi*16 + (lane&15)) * 256 + kk*32 + (lane>>4)*8 + e]
__global__ __launch_bounds__(256) void k_cvt_w(const float* __restrict__ w,
                                               u16* __restrict__ wf)
{
    const int idx = blockIdx.x * 256 + threadIdx.x;   // 0..24575
    const int l   = idx & 63;
    const int mi  = (idx >> 6) & 3;
    const int wm  = (idx >> 8) & 1;
    const int kk  = (idx >> 9) & 7;
    const int ob  = idx >> 12;
    const int row = ob * 128 + wm * 64 + mi * 16 + (l & 15);
    const int col = kk * 32 + (l >> 4) * 8;
    const float* src = w + (size_t)row * 256 + col;
    u16x8 o;
    #pragma unroll
    for (int j = 0; j < 8; ++j) o[j] = f2bf(src[j]);
    *(u16x8*)(wf + (size_t)idx * 8) = o;
}

// ---------------- K1: qkv_t[j][o] MFMA, q-softmax fused in epilogue ---------
// grid: 1-D, CF*32*6 blocks; XCD-chunked swizzle, o fastest within XCD.
// A (wq_f) coalesced global->reg, 1-ahead; B (xbf) 3-deep LDS, counted vmcnt.
__global__ __launch_bounds__(256) void k_qkv_mfma(const u16* __restrict__ xbf,
                                                  const u16* __restrict__ wq,
                                                  u16* __restrict__ qkv)
{
    const int tid = threadIdx.x;
    const int lane = tid & 63, wave = tid >> 6;
    const int ln = lane & 15, quad = lane >> 4;
    const int wm = wave & 1, wn = wave >> 1;

    const int chunk = gridDim.x >> 3;
    const int newid = (blockIdx.x & 7) * chunk + (blockIdx.x >> 3);
    const int o0 = (newid % 6) * 128;   // M tile (wq rows) — fastest
    const int j0 = (newid / 6) * 128;   // N tile (x rows)

    // LDS: 3 x 8KB B-staging (mod-3), overlaid with 34.8KB out-tile
    __shared__ __align__(16) u16 sm[128 * 136];

    f32x4 acc[4][4] = {};
    const int lrow = lane >> 2;
    const int lk8 = ((lane & 3) ^ ((lrow >> 1) & 3)) * 8;   // pre-swizzled src
    const int sw8 = (quad ^ ((ln >> 1) & 3)) * 8;           // swizzled ds_read

    const u16* gB = xbf + (size_t)j0 * 256;
    const int r0 = wave * 32 + lrow;
    // A fragment-order base: chunk (ob, t, wm, mi, lane) at
    //   ob*32768 + t*4096 + wm*2048 + mi*512 + lane*8   (u16 units)
    const u16* gAf = wq + (size_t)(o0 >> 7) * 32768 + wm * 2048 + lane * 8;

    bf16x8 afr[2][4];

    // prologue: B(0)->buf0, A(0)->regs, B(1)->buf1; drain B0+A0, keep B1 flying
    async16(gB + (size_t)r0 * 256 + lk8,        sm + (wave*2) * 512);
    async16(gB + (size_t)(r0+16) * 256 + lk8,   sm + (wave*2+1) * 512);
    #pragma unroll
    for (int mi = 0; mi < 4; ++mi)
        afr[0][mi] = *(const bf16x8*)(gAf + mi * 512);
    async16(gB + (size_t)r0 * 256 + 32 + lk8,      sm + 4096 + (wave*2) * 512);
    async16(gB + (size_t)(r0+16) * 256 + 32 + lk8, sm + 4096 + (wave*2+1) * 512);
    asm volatile("s_waitcnt vmcnt(2)\n\ts_barrier" ::: "memory");

    #pragma unroll
    for (int t = 0; t < 8; ++t) {
        if (t < 7) {   // A(t+1) regs FIRST (so waits on them never drain B)
            #pragma unroll
            for (int mi = 0; mi < 4; ++mi)
                afr[(t+1) & 1][mi] =
                    *(const bf16x8*)(gAf + (t+1) * 4096 + mi * 512);
        }
        if (t < 6) {   // B(t+2) stage — 2-deep, lands 2 barriers out
            u16* Bn = sm + ((t + 2) % 3) * 4096;
            const int kk2 = (t + 2) * 32;
            async16(gB + (size_t)r0 * 256 + kk2 + lk8,      Bn + (wave*2) * 512);
            async16(gB + (size_t)(r0+16) * 256 + kk2 + lk8, Bn + (wave*2+1) * 512);
        }
        const u16* Bs = sm + (t % 3) * 4096;
        bf16x8 bfv[4];
        #pragma unroll
        for (int ni = 0; ni < 4; ++ni)
            bfv[ni] = *(const bf16x8*)&Bs[(wn * 64 + ni * 16 + ln) * 32 + sw8];
        #pragma unroll
        for (int mi = 0; mi < 4; ++mi)
            #pragma unroll
            for (int ni = 0; ni < 4; ++ni)
                acc[mi][ni] = __builtin_amdgcn_mfma_f32_16x16x32_bf16(
                    afr[t & 1][mi], bfv[ni], acc[mi][ni], 0, 0, 0);
        // counted waits: newest 6 = {A(t+1) regs 4, B(t+2) stage 2} under any
        // intra-region order -> vmcnt(6) guarantees B(t+1) landed. Never 0.
        if (t < 6)       asm volatile("s_waitcnt vmcnt(6)\n\ts_barrier" ::: "memory");
        else if (t == 6) asm volatile("s_waitcnt vmcnt(4)\n\ts_barrier" ::: "memory");
    }

    // Assemble [j][o] bf16 tile in LDS (stride 136)
    __syncthreads();
    u16* outl = sm;
    #pragma unroll
    for (int mi = 0; mi < 4; ++mi)
        #pragma unroll
        for (int ni = 0; ni < 4; ++ni) {
            const int jl = wn * 64 + ni * 16 + ln;
            const int ob = wm * 64 + mi * 16 + quad * 4;
            u16x4 u;
            u[0] = f2bf(acc[mi][ni][0]); u[1] = f2bf(acc[mi][ni][1]);
            u[2] = f2bf(acc[mi][ni][2]); u[3] = f2bf(acc[mi][ni][3]);
            *(u16x4*)&outl[jl * 136 + ob] = u;
        }
    __syncthreads();

    if (o0 < 256) {
        // q tiles: softmax over each 32-col head group, * 1/sqrt(32)
        #pragma unroll
        for (int t = 0; t < 2; ++t) {
            const int idx = t * 256 + tid;
            const int r = idx >> 2, hh = idx & 3;
            const u16* p = &outl[r * 136 + hh * 32];
            float v[32];
            float m = -1e30f;
            #pragma unroll
            for (int g = 0; g < 4; ++g) {
                u16x8 u = *(const u16x8*)(p + g * 8);
                #pragma unroll
                for (int i = 0; i < 8; ++i) {
                    v[g * 8 + i] = bf2f(u[i]);
                    m = fmaxf(m, v[g * 8 + i]);
                }
            }
            float s = 0.f;
            #pragma unroll
            for (int i = 0; i < 32; ++i) { v[i] = __expf(v[i] - m); s += v[i]; }
            const float inv = 0.17677669529663687f / s;
            u16* q = qkv + (size_t)(j0 + r) * 768 + o0 + hh * 32;
            #pragma unroll
            for (int g = 0; g < 4; ++g) {
                u16x8 ov;
                #pragma unroll
                for (int i = 0; i < 8; ++i) ov[i] = f2bf(v[g * 8 + i] * inv);
                *(u16x8*)(q + g * 8) = ov;
            }
        }
    } else {
        #pragma unroll
        for (int r = 0; r < 8; ++r) {
            const int row = r * 16 + (tid >> 4);
            const int cb = (tid & 15) * 8;
            u32x4 v = *(const u32x4*)&outl[row * 136 + cb];
            *(u32x4*)(qkv + (size_t)(j0 + row) * 768 + o0 + cb) = v;
        }
    }
}

// ---------------- S1: online (m,s) partials per k-col, per (fl, j-split) ----
__global__ __launch_bounds__(256) void k_kstat1(const u16* __restrict__ qkv,
                                                float* __restrict__ sp)
{
    const int js = blockIdx.x, fl = blockIdx.y;
    const int tid = threadIdx.x;
    const int s = tid >> 5, g = tid & 31;
    const u16* base = qkv + ((size_t)fl * 4096 + js * 256 + s) * 768 + 256 + g * 8;
    float m[8], sm[8];
    #pragma unroll
    for (int i = 0; i < 8; ++i) { m[i] = -1e30f; sm[i] = 0.f; }
    for (int it = 0; it < 32; ++it) {
        u16x8 u = *(const u16x8*)(base + (size_t)it * 8 * 768);
        #pragma unroll
        for (int i = 0; i < 8; ++i) {
            float v = bf2f(u[i]);
            float nm = fmaxf(m[i], v);
            sm[i] = sm[i] * __expf(m[i] - nm) + __expf(v - nm);
            m[i] = nm;
        }
    }
    __shared__ float Lm[8][256], Ls[8][256];
    #pragma unroll
    for (int i = 0; i < 8; ++i) { Lm[s][g * 8 + i] = m[i]; Ls[s][g * 8 + i] = sm[i]; }
    __syncthreads();
    const int col = tid;
    float M = -1e30f;
    #pragma unroll
    for (int k = 0; k < 8; ++k) M = fmaxf(M, Lm[k][col]);
    float S = 0.f;
    #pragma unroll
    for (int k = 0; k < 8; ++k) S += Ls[k][col] * __expf(Lm[k][col] - M);
    float* o = sp + (((size_t)fl * 16 + js) * 256 + col) * 2;
    o[0] = M; o[1] = S;
}

// ---------------- S2: combine 16 partials -> (M, 1/S) -----------------------
__global__ __launch_bounds__(256) void k_kstat2(const float* __restrict__ sp,
                                                float* __restrict__ stat)
{
    const int fl = blockIdx.x, col = threadIdx.x;
    float mv[16], sv[16];
    float M = -1e30f;
    #pragma unroll
    for (int js = 0; js < 16; ++js) {
        const float* p = sp + (((size_t)fl * 16 + js) * 256 + col) * 2;
        mv[js] = p[0]; sv[js] = p[1];
        M = fmaxf(M, mv[js]);
    }
    float S = 0.f;
    #pragma unroll
    for (int js = 0; js < 16; ++js) S += sv[js] * __expf(mv[js] - M);
    float* o = stat + ((size_t)fl * 256 + col) * 2;
    o[0] = M; o[1] = 1.0f / S;
}

// ---------------- CX: P[h][d][e] += exp(k-M)*v, per (fl, j-split) -----------
__global__ __launch_bounds__(256) void k_ctx(const u16* __restrict__ qkv,
                                             const float* __restrict__ stat,
                                             float* __restrict__ P)
{
    const int js = blockIdx.x, fl = blockIdx.y;
    const int tid = threadIdx.x;
    const int ls = tid >> 5, lg = tid & 31;                  // staging role
    const int h = tid >> 5, dg = (tid >> 3) & 3, eg = tid & 7;  // acc role
    const int d0 = dg * 8, e0 = eg * 4;

    float Mg[8];
    #pragma unroll
    for (int i = 0; i < 8; ++i) Mg[i] = stat[((size_t)fl * 256 + lg * 8 + i) * 2];

    __shared__ float expk[8][264], vbuf[8][264];
    f32x4 acc[8] = {};
    const u16* kbase = qkv + ((size_t)fl * 4096 + js * 256 + ls) * 768 + 256 + lg * 8;

    for (int ch = 0; ch < 32; ++ch) {
        const u16* kp = kbase + (size_t)ch * 8 * 768;
        u16x8 ku = *(const u16x8*)kp;
        u16x8 vu = *(const u16x8*)(kp + 256);
        __syncthreads();
        #pragma unroll
        for (int i = 0; i < 8; ++i) {
            expk[ls][lg * 8 + i] = __expf(bf2f(ku[i]) - Mg[i]);
            vbuf[ls][lg * 8 + i] = bf2f(vu[i]);
        }
        __syncthreads();
        #pragma unroll
        for (int rr = 0; rr < 8; ++rr) {
            f32x4 w0 = *(const f32x4*)&expk[rr][h * 32 + d0];
            f32x4 w1 = *(const f32x4*)&expk[rr][h * 32 + d0 + 4];
            f32x4 vv = *(const f32x4*)&vbuf[rr][h * 32 + e0];
            #pragma unroll
            for (int ei = 0; ei < 4; ++ei) {
                acc[0][ei] = fmaf(w0[0], vv[ei], acc[0][ei]);
                acc[1][ei] = fmaf(w0[1], vv[ei], acc[1][ei]);
                acc[2][ei] = fmaf(w0[2], vv[ei], acc[2][ei]);
                acc[3][ei] = fmaf(w0[3], vv[ei], acc[3][ei]);
                acc[4][ei] = fmaf(w1[0], vv[ei], acc[4][ei]);
                acc[5][ei] = fmaf(w1[1], vv[ei], acc[5][ei]);
                acc[6][ei] = fmaf(w1[2], vv[ei], acc[6][ei]);
                acc[7][ei] = fmaf(w1[3], vv[ei], acc[7][ei]);
            }
        }
    }
    float* o = P + ((size_t)fl * 16 + js) * 8192 + (h * 32 + d0) * 32 + e0;
    #pragma unroll
    for (int di = 0; di < 8; ++di) *(f32x4*)(o + di * 32) = acc[di];
}

// ---------------- W2: sum partials, *invS, fold w_out -> w2_f (frag order) --
__global__ __launch_bounds__(256) void k_w2fold(const float* __restrict__ P,
                                                const float* __restrict__ stat,
                                                const float* __restrict__ w_out,
                                                u16* __restrict__ w2)
{
    const int h = blockIdx.x, fl = blockIdx.y;
    const int tid = threadIdx.x;
    __shared__ float Cs[32 * 33];

    const float* p0 = P + (size_t)fl * 16 * 8192 + h * 1024 + tid * 4;
    f32x4 sum = {0.f, 0.f, 0.f, 0.f};
    #pragma unroll
    for (int js = 0; js < 16; ++js) {
        f32x4 v = *(const f32x4*)(p0 + (size_t)js * 8192);
        sum[0] += v[0]; sum[1] += v[1]; sum[2] += v[2]; sum[3] += v[3];
    }
    const int d = tid >> 3, e4 = (tid & 7) * 4;
    const float inv = stat[((size_t)fl * 256 + h * 32 + d) * 2 + 1];
    Cs[d * 33 + e4 + 0] = sum[0] * inv;
    Cs[d * 33 + e4 + 1] = sum[1] * inv;
    Cs[d * 33 + e4 + 2] = sum[2] * inv;
    Cs[d * 33 + e4 + 3] = sum[3] * inv;
    __syncthreads();

    const int o = tid;
    float a2[32];
    #pragma unroll
    for (int dd = 0; dd < 32; ++dd) a2[dd] = 0.f;
    for (int e = 0; e < 32; ++e) {
        const float wv = w_out[(size_t)o * 256 + h * 32 + e];
        #pragma unroll
        for (int dd = 0; dd < 32; ++dd) a2[dd] = fmaf(wv, Cs[dd * 33 + e], a2[dd]);
    }
    // fragment-order write: value (row o, col c2 = h*32 + g*8 + i) -> chunk
    //   (((ob*8 + h)*2 + wn)*4 + ni)*64 + (g*16 + ln), element i
    const int ob = o >> 7, rr = o & 127;
    const int wn = rr >> 6, ni = (rr >> 4) & 3, lnn = rr & 15;
    u16* wp = w2 + (size_t)fl * 65536
                 + (size_t)((((ob * 8 + h) * 2 + wn) * 4 + ni) * 64) * 8;
    #pragma unroll
    for (int g = 0; g < 4; ++g) {
        u16x8 ov;
        #pragma unroll
        for (int i = 0; i < 8; ++i) ov[i] = f2bf(a2[g * 8 + i]);
        *(u16x8*)(wp + (size_t)(g * 16 + lnn) * 8) = ov;
    }
}

// ---------------- K5: out = MFMA(q, W2) + b_out, fp32 direct store ----------
// grid: 1-D, CF*32*2 blocks; XCD-chunked swizzle, o fastest within XCD.
// A (q) 3-deep LDS staging; B (w2_f) coalesced global->reg, 1-ahead.
__global__ __launch_bounds__(256) void k_out_mfma(const u16* __restrict__ qkv,
                                                  const u16* __restrict__ w2,
                                                  const float* __restrict__ b_out,
                                                  float* __restrict__ out, int fr0)
{
    const int tid = threadIdx.x;
    const int lane = tid & 63, wave = tid >> 6;
    const int ln = lane & 15, quad = lane >> 4;
    const int wm = wave & 1, wn = wave >> 1;

    const int chunk = gridDim.x >> 3;
    const int newid = (blockIdx.x & 7) * chunk + (blockIdx.x >> 3);
    const int o0 = (newid & 1) * 128;   // N tile (W2 rows) — fastest
    const int j0 = (newid >> 1) * 128;  // M tile (q rows, local j)

    const int fl = j0 >> 12;
    const int frame = fr0 + fl, b = frame >> 4, f = frame & 15;
    const int nb = j0 & 4095;
    const u16* w2f = w2 + (size_t)fl * 65536;

    __shared__ __align__(16) u16 sm[12288];   // 3 x 8KB A-staging

    f32x4 acc[4][4] = {};
    const int lrow = lane >> 2;
    const int lk8 = ((lane & 3) ^ ((lrow >> 1) & 3)) * 8;   // pre-swizzled src
    const int sw8 = (quad ^ ((ln >> 1) & 3)) * 8;           // swizzled ds_read

    const u16* gA = qkv + (size_t)j0 * 768;
    const int r0 = wave * 32 + lrow;
    const u16* gBf = w2f + (size_t)(o0 >> 7) * 32768 + wn * 2048 + lane * 8;

    bf16x8 bfr[2][4];

    // prologue: A(0)->buf0, B(0)->regs, A(1)->buf1
    async16(gA + (size_t)r0 * 768 + lk8,        sm + (wave*2) * 512);
    async16(gA + (size_t)(r0+16) * 768 + lk8,   sm + (wave*2+1) * 512);
    #pragma unroll
    for (int ni = 0; ni < 4; ++ni)
        bfr[0][ni] = *(const bf16x8*)(gBf + ni * 512);
    async16(gA + (size_t)r0 * 768 + 32 + lk8,      sm + 4096 + (wave*2) * 512);
    async16(gA + (size_t)(r0+16) * 768 + 32 + lk8, sm + 4096 + (wave*2+1) * 512);
    asm volatile("s_waitcnt vmcnt(2)\n\ts_barrier" ::: "memory");

    #pragma unroll
    for (int t = 0; t < 8; ++t) {
        if (t < 7) {   // B(t+1) regs first
            #pragma unroll
            for (int ni = 0; ni < 4; ++ni)
                bfr[(t+1) & 1][ni] =
                    *(const bf16x8*)(gBf + (t+1) * 4096 + ni * 512);
        }
        if (t < 6) {   // A(t+2) stage
            u16* An = sm + ((t + 2) % 3) * 4096;
            const int kk2 = (t + 2) * 32;
            async16(gA + (size_t)r0 * 768 + kk2 + lk8,      An + (wave*2) * 512);
            async16(gA + (size_t)(r0+16) * 768 + kk2 + lk8, An + (wave*2+1) * 512);
        }
        const u16* As = sm + (t % 3) * 4096;
        bf16x8 af[4];
        #pragma unroll
        for (int mi = 0; mi < 4; ++mi)
            af[mi] = *(const bf16x8*)&As[(wm * 64 + mi * 16 + ln) * 32 + sw8];
        #pragma unroll
        for (int mi = 0; mi < 4; ++mi)
            #pragma unroll
            for (int ni = 0; ni < 4; ++ni)
                acc[mi][ni] = __builtin_amdgcn_mfma_f32_16x16x32_bf16(
                    af[mi], bfr[t & 1][ni], acc[mi][ni], 0, 0, 0);
        if (t < 6)       asm volatile("s_waitcnt vmcnt(6)\n\ts_barrier" ::: "memory");
        else if (t == 6) asm volatile("s_waitcnt vmcnt(4)\n\ts_barrier" ::: "memory");
    }

    float* obase = out + (size_t)b * XB_STRIDE + (size_t)f * 4096;
    #pragma unroll
    for (int ni = 0; ni < 4; ++ni) {
        const int o = o0 + wn * 64 + ni * 16 + ln;
        const float bias = b_out[o];
        #pragma unroll
        for (int mi = 0; mi < 4; ++mi) {
            const int jn = nb + wm * 64 + mi * 16 + quad * 4;
            f32x4 v = acc[mi][ni];
            v[0] += bias; v[1] += bias; v[2] += bias; v[3] += bias;
            *(f32x4*)(obase + (size_t)o * XCH_STRIDE + jn) = v;
        }
    }
}

// ---------------------------------------------------------------------------
extern "C" void kernel_launch(void* const* d_in, const int* in_sizes, int n_in,
                              void* d_out, int out_size, void* d_ws, size_t ws_size,
                              hipStream_t stream)
{
    const float* x     = (const float*)d_in[0];
    const float* w_qkv = (const float*)d_in[1];
    const float* w_out = (const float*)d_in[2];
    const float* b_out = (const float*)d_in[3];
    float* out = (float*)d_out;

    // ws per frame: xbf 2MB + qkv 6MB + w2 128KB + sp 32KB + stat 2KB + P 512KB
    const size_t per_frame = (size_t)4096 * 256 * 2 + (size_t)4096 * 768 * 2
                           + 65536 * 2 + 16 * 512 * 4 + 512 * 4 + 16 * 8192 * 4;
    const size_t wq_bytes = 768 * 256 * 2;
    int CF = 32;
    while (CF > 1 && (size_t)CF * per_frame + wq_bytes > ws_size) CF >>= 1;

    u16* wq_bf  = (u16*)d_ws;
    u16* xbf    = wq_bf + 768 * 256;
    u16* qkv    = xbf + (size_t)CF * 4096 * 256;
    u16* w2     = qkv + (size_t)CF * 4096 * 768;
    float* sp   = (float*)(w2 + (size_t)CF * 65536);
    float* stat = sp + (size_t)CF * 16 * 256 * 2;
    float* P    = stat + (size_t)CF * 256 * 2;

    k_cvt_w<<<96, 256, 0, stream>>>(w_qkv, wq_bf);
    for (int fr0 = 0; fr0 < 32; fr0 += CF) {
        k_cvt_x   <<<dim3(64, 4, CF), 256, 0, stream>>>(x, xbf, fr0);
        k_qkv_mfma<<<CF * 32 * 6, 256, 0, stream>>>(xbf, wq_bf, qkv);
        k_kstat1  <<<dim3(16, CF), 256, 0, stream>>>(qkv, sp);
        k_kstat2  <<<CF, 256, 0, stream>>>(sp, stat);
        k_ctx     <<<dim3(16, CF), 256, 0, stream>>>(qkv, stat, P);
        k_w2fold  <<<dim3(8, CF), 256, 0, stream>>>(P, stat, w_out, w2);
        k_out_mfma<<<CF * 32 * 2, 256, 0, stream>>>(qkv, w2, b_out, out, fr0);
    }
}